// Round 1
// baseline (629.185 us; speedup 1.0000x reference)
//
#include <hip/hip_runtime.h>
#include <hip/hip_bf16.h>

#define N_NODES 100000
#define N_EDGES 1600000

// ---------------------------------------------------------------------------
// Layer-1 scatter: sum1[dst][f] += x[src][f] (f=0..7), deg[dst] += 1
// 8 lanes per edge, grid-stride.
// ---------------------------------------------------------------------------
__global__ void scatter1(const float* __restrict__ x,
                         const int* __restrict__ src,
                         const int* __restrict__ dst,
                         float* __restrict__ sum1,
                         float* __restrict__ deg) {
    const int total = N_EDGES * 8;
    const int stride = gridDim.x * blockDim.x;
    for (int i = blockIdx.x * blockDim.x + threadIdx.x; i < total; i += stride) {
        int e = i >> 3;
        int f = i & 7;
        int s = src[e];
        int d = dst[e];
        atomicAdd(&sum1[d * 8 + f], x[s * 8 + f]);
        if (f == 0) atomicAdd(&deg[d], 1.0f);
    }
}

// ---------------------------------------------------------------------------
// Layer-1 node transform: h1 = relu((sum1/deg) @ W1_l + b1 + x @ W1_r)
// one thread per (node, out_feature); weights in LDS.
// ---------------------------------------------------------------------------
__global__ void node1(const float* __restrict__ x,
                      const float* __restrict__ sum1,
                      const float* __restrict__ deg,
                      const float* __restrict__ W1l,  // (8,64) row-major
                      const float* __restrict__ b1,   // (64)
                      const float* __restrict__ W1r,  // (8,64)
                      float* __restrict__ h1) {
    __shared__ float wl[8 * 64];
    __shared__ float wr[8 * 64];
    __shared__ float bb[64];
    for (int i = threadIdx.x; i < 512; i += blockDim.x) {
        wl[i] = W1l[i];
        wr[i] = W1r[i];
    }
    if (threadIdx.x < 64) bb[threadIdx.x] = b1[threadIdx.x];
    __syncthreads();

    const int total = N_NODES * 64;
    const int stride = gridDim.x * blockDim.x;
    for (int i = blockIdx.x * blockDim.x + threadIdx.x; i < total; i += stride) {
        int node = i >> 6;
        int j = i & 63;
        float inv = 1.0f / fmaxf(deg[node], 1.0f);
        float acc = bb[j];
#pragma unroll
        for (int k = 0; k < 8; k++) {
            float m = sum1[node * 8 + k] * inv;
            acc += m * wl[k * 64 + j] + x[node * 8 + k] * wr[k * 64 + j];
        }
        h1[i] = fmaxf(acc, 0.0f);
    }
}

// ---------------------------------------------------------------------------
// Layer-2 scatter: sum2[dst][f] += h1[src][f] (f=0..63)
// 64 lanes per edge, grid-stride. THE hot kernel (102.4M fp32 atomics).
// ---------------------------------------------------------------------------
__global__ void scatter2(const float* __restrict__ h1,
                         const int* __restrict__ src,
                         const int* __restrict__ dst,
                         float* __restrict__ sum2) {
    const long long total = (long long)N_EDGES * 64;
    const long long stride = (long long)gridDim.x * blockDim.x;
    for (long long i = (long long)blockIdx.x * blockDim.x + threadIdx.x; i < total; i += stride) {
        int e = (int)(i >> 6);
        int f = (int)(i & 63);
        int s = src[e];
        int d = dst[e];
        atomicAdd(&sum2[(long long)d * 64 + f], h1[(long long)s * 64 + f]);
    }
}

// ---------------------------------------------------------------------------
// Layer-2 node transform + fused global mean-pool partial sums:
// h2 = relu((sum2/deg) @ W2_l + b2 + h1 @ W2_r); gsum[j] += sum_nodes h2[.,j]
// block = 256 threads = 4 node-slots x 64 features. Weights (32 KB) in LDS.
// ---------------------------------------------------------------------------
__global__ void node2(const float* __restrict__ h1,
                      const float* __restrict__ sum2,
                      const float* __restrict__ deg,
                      const float* __restrict__ W2l,  // (64,64)
                      const float* __restrict__ b2,   // (64)
                      const float* __restrict__ W2r,  // (64,64)
                      float* __restrict__ gsum) {
    __shared__ float wl[64 * 64];
    __shared__ float wr[64 * 64];
    __shared__ float bb[64];
    __shared__ float mrow[4][64];
    __shared__ float hrow[4][64];
    __shared__ float part[4][64];

    for (int i = threadIdx.x; i < 4096; i += blockDim.x) {
        wl[i] = W2l[i];
        wr[i] = W2r[i];
    }
    if (threadIdx.x < 64) bb[threadIdx.x] = b2[threadIdx.x];
    __syncthreads();

    const int j = threadIdx.x & 63;
    const int slot = threadIdx.x >> 6;  // 0..3
    float accsum = 0.0f;

    for (int node0 = blockIdx.x * 4; node0 < N_NODES; node0 += gridDim.x * 4) {
        int node = node0 + slot;
        __syncthreads();  // protect mrow/hrow reuse across iterations
        if (node < N_NODES) {
            float inv = 1.0f / fmaxf(deg[node], 1.0f);
            mrow[slot][j] = sum2[node * 64 + j] * inv;
            hrow[slot][j] = h1[node * 64 + j];
        }
        __syncthreads();
        if (node < N_NODES) {
            float acc = bb[j];
#pragma unroll 8
            for (int k = 0; k < 64; k++) {
                acc += mrow[slot][k] * wl[k * 64 + j] + hrow[slot][k] * wr[k * 64 + j];
            }
            accsum += fmaxf(acc, 0.0f);
        }
    }

    part[slot][j] = accsum;
    __syncthreads();
    if (threadIdx.x < 64) {
        float s = part[0][j] + part[1][j] + part[2][j] + part[3][j];
        atomicAdd(&gsum[j], s);
    }
}

// ---------------------------------------------------------------------------
// Head: g = gsum/N; a = relu(g@fc1_W+fc1_b); a = a@fc2_W+fc2_b; softmax -> out
// single block, 64 threads.
// ---------------------------------------------------------------------------
__global__ void head(const float* __restrict__ gsum,
                     const float* __restrict__ fc1W,  // (64,64)
                     const float* __restrict__ fc1b,  // (64)
                     const float* __restrict__ fc2W,  // (64,10)
                     const float* __restrict__ fc2b,  // (10)
                     float* __restrict__ out) {
    __shared__ float g[64];
    __shared__ float a1[64];
    __shared__ float a2[10];
    int j = threadIdx.x;
    g[j] = gsum[j] * (1.0f / (float)N_NODES);
    __syncthreads();
    float acc = fc1b[j];
    for (int k = 0; k < 64; k++) acc += g[k] * fc1W[k * 64 + j];
    a1[j] = fmaxf(acc, 0.0f);
    __syncthreads();
    if (j < 10) {
        float acc2 = fc2b[j];
        for (int k = 0; k < 64; k++) acc2 += a1[k] * fc2W[k * 10 + j];
        a2[j] = acc2;
    }
    __syncthreads();
    if (j == 0) {
        float mx = -1e30f;
        for (int i = 0; i < 10; i++) mx = fmaxf(mx, a2[i]);
        float s = 0.0f;
        float e[10];
        for (int i = 0; i < 10; i++) {
            e[i] = expf(a2[i] - mx);
            s += e[i];
        }
        float invs = 1.0f / s;
        for (int i = 0; i < 10; i++) out[i] = e[i] * invs;
    }
}

extern "C" void kernel_launch(void* const* d_in, const int* in_sizes, int n_in,
                              void* d_out, int out_size, void* d_ws, size_t ws_size,
                              hipStream_t stream) {
    const float* x    = (const float*)d_in[0];
    const int*   ei   = (const int*)d_in[1];
    const float* W1l  = (const float*)d_in[2];
    const float* b1   = (const float*)d_in[3];
    const float* W1r  = (const float*)d_in[4];
    const float* W2l  = (const float*)d_in[5];
    const float* b2   = (const float*)d_in[6];
    const float* W2r  = (const float*)d_in[7];
    const float* fc1W = (const float*)d_in[8];
    const float* fc1b = (const float*)d_in[9];
    const float* fc2W = (const float*)d_in[10];
    const float* fc2b = (const float*)d_in[11];
    float* out = (float*)d_out;

    const int* src = ei;             // edge_index[0]
    const int* dst = ei + N_EDGES;   // edge_index[1]

    // workspace layout (floats): deg | sum1 | sum2 | gsum | h1
    float* ws   = (float*)d_ws;
    float* deg  = ws;
    float* sum1 = deg + N_NODES;
    float* sum2 = sum1 + (size_t)N_NODES * 8;
    float* gsum = sum2 + (size_t)N_NODES * 64;
    float* h1   = gsum + 64;

    // zero all accumulator regions (deg..gsum are contiguous)
    size_t zero_bytes = ((size_t)N_NODES * (1 + 8 + 64) + 64) * sizeof(float);
    hipMemsetAsync(d_ws, 0, zero_bytes, stream);

    scatter1<<<2048, 256, 0, stream>>>(x, src, dst, sum1, deg);
    node1<<<4096, 256, 0, stream>>>(x, sum1, deg, W1l, b1, W1r, h1);
    scatter2<<<8192, 256, 0, stream>>>(h1, src, dst, sum2);
    node2<<<2048, 256, 0, stream>>>(h1, sum2, deg, W2l, b2, W2r, gsum);
    head<<<1, 64, 0, stream>>>(gsum, fc1W, fc1b, fc2W, fc2b, out);
}

// Round 2
// 479.804 us; speedup vs baseline: 1.3113x; 1.3113x over previous
//
#include <hip/hip_runtime.h>
#include <hip/hip_bf16.h>

#define N_NODES 100000
#define N_EDGES 1600000
#define NBLK_SCAN ((N_NODES + 255) / 256)   // 391

// ---------------------------------------------------------------------------
// CSR build: histogram of dst degrees (int atomics)
// ---------------------------------------------------------------------------
__global__ void hist_kernel(const int* __restrict__ dst, int* __restrict__ deg) {
    int stride = gridDim.x * blockDim.x;
    for (int e = blockIdx.x * blockDim.x + threadIdx.x; e < N_EDGES; e += stride)
        atomicAdd(&deg[dst[e]], 1);
}

// per-256-block sums of deg
__global__ void scanA(const int* __restrict__ deg, int* __restrict__ bsum) {
    __shared__ int s[256];
    int gid = blockIdx.x * 256 + threadIdx.x;
    s[threadIdx.x] = (gid < N_NODES) ? deg[gid] : 0;
    __syncthreads();
    for (int d = 128; d > 0; d >>= 1) {
        if (threadIdx.x < d) s[threadIdx.x] += s[threadIdx.x + d];
        __syncthreads();
    }
    if (threadIdx.x == 0) bsum[blockIdx.x] = s[0];
}

// exclusive scan of block sums (single block, Hillis-Steele over 512)
__global__ void scanB(const int* __restrict__ bsum, int* __restrict__ boff) {
    __shared__ int s[512];
    int i = threadIdx.x;
    int v = (i < NBLK_SCAN) ? bsum[i] : 0;
    s[i] = v;
    __syncthreads();
    for (int d = 1; d < 512; d <<= 1) {
        int t = (i >= d) ? s[i - d] : 0;
        __syncthreads();
        s[i] += t;
        __syncthreads();
    }
    if (i < NBLK_SCAN) boff[i] = s[i] - v;   // exclusive offset for block i
}

// in-block exclusive scan + block offset -> row_start
__global__ void scanC(const int* __restrict__ deg, const int* __restrict__ boff,
                      int* __restrict__ row_start) {
    __shared__ int s[256];
    int gid = blockIdx.x * 256 + threadIdx.x;
    int v = (gid < N_NODES) ? deg[gid] : 0;
    s[threadIdx.x] = v;
    __syncthreads();
    for (int d = 1; d < 256; d <<= 1) {
        int t = (threadIdx.x >= d) ? s[threadIdx.x - d] : 0;
        __syncthreads();
        s[threadIdx.x] += t;
        __syncthreads();
    }
    if (gid < N_NODES) row_start[gid] = boff[blockIdx.x] + s[threadIdx.x] - v;
    if (gid == 0) row_start[N_NODES] = N_EDGES;
}

// fill CSR adjacency (src lists grouped by dst)
__global__ void fill_kernel(const int* __restrict__ src, const int* __restrict__ dst,
                            const int* __restrict__ row_start, int* __restrict__ cursor,
                            int* __restrict__ csr) {
    int stride = gridDim.x * blockDim.x;
    for (int e = blockIdx.x * blockDim.x + threadIdx.x; e < N_EDGES; e += stride) {
        int d = dst[e];
        int pos = atomicAdd(&cursor[d], 1);
        csr[row_start[d] + pos] = src[e];
    }
}

// ---------------------------------------------------------------------------
// Layer 1 fused: gather-mean of x (8 feats) + transform -> h1 (N,64), relu
// wave = 8 nodes x 8 features (group g = lane>>3, f = lane&7)
// ---------------------------------------------------------------------------
__global__ __launch_bounds__(256) void layer1(
    const float* __restrict__ x, const int* __restrict__ row_start,
    const int* __restrict__ csr, const float* __restrict__ W1l,
    const float* __restrict__ b1, const float* __restrict__ W1r,
    float* __restrict__ h1) {
    __shared__ float wl[512], wr[512], bb[64];
    for (int i = threadIdx.x; i < 512; i += 256) { wl[i] = W1l[i]; wr[i] = W1r[i]; }
    if (threadIdx.x < 64) bb[threadIdx.x] = b1[threadIdx.x];
    __syncthreads();

    const int lane = threadIdx.x & 63;
    const int f = lane & 7;
    const int g = lane >> 3;
    const int gwid = blockIdx.x * 4 + (threadIdx.x >> 6);
    const int nwaves = gridDim.x * 4;

    for (int base = gwid * 8; base < N_NODES; base += nwaves * 8) {
        int node = base + g;
        bool valid = node < N_NODES;
        int nodec = valid ? node : (N_NODES - 1);
        int rs = row_start[nodec];
        int re = row_start[nodec + 1];
        float acc = 0.0f;
        for (int t = rs; t < re; ++t) {
            int s = csr[t];
            acc += x[s * 8 + f];
        }
        float inv = 1.0f / fmaxf((float)(re - rs), 1.0f);
        float mean = acc * inv;
        float xv = x[nodec * 8 + f];
        // broadcast the 8 mean/self features within each 8-lane group
        float m[8], xk[8];
        int gbase = lane & 56;
#pragma unroll
        for (int k = 0; k < 8; k++) {
            m[k]  = __shfl(mean, gbase + k);
            xk[k] = __shfl(xv,   gbase + k);
        }
        // lane f computes outputs j = f + 8u
#pragma unroll
        for (int u = 0; u < 8; u++) {
            int j = f + 8 * u;
            float a = bb[j];
#pragma unroll
            for (int k = 0; k < 8; k++)
                a += m[k] * wl[k * 64 + j] + xk[k] * wr[k * 64 + j];
            if (valid) h1[node * 64 + j] = fmaxf(a, 0.0f);
        }
    }
}

// ---------------------------------------------------------------------------
// Layer 2 fused: gather-mean of h1 (64 feats) + transform + relu + global pool
// wave per node; weight columns in registers (128 VGPR); mean/self rows
// broadcast via same-address float4 LDS reads.
// ---------------------------------------------------------------------------
__global__ __launch_bounds__(256, 2) void layer2(
    const float* __restrict__ h1, const int* __restrict__ row_start,
    const int* __restrict__ csr, const float* __restrict__ W2l,
    const float* __restrict__ b2, const float* __restrict__ W2r,
    float* __restrict__ gsum) {
    __shared__ float st[4][2][64];
    __shared__ float part[4][64];
    const int lane = threadIdx.x & 63;
    const int w = threadIdx.x >> 6;

    float wl[64], wr[64];
#pragma unroll
    for (int k = 0; k < 64; k++) {
        wl[k] = W2l[k * 64 + lane];
        wr[k] = W2r[k * 64 + lane];
    }
    float bv = b2[lane];

    const int gwid = blockIdx.x * 4 + w;
    const int nwaves = gridDim.x * 4;
    float pool = 0.0f;

    for (int node = gwid; node < N_NODES; node += nwaves) {
        int rs = row_start[node];
        int re = row_start[node + 1];
        float acc = 0.0f;
        int t = rs;
        for (; t + 4 <= re; t += 4) {
            int s0 = csr[t], s1 = csr[t + 1], s2 = csr[t + 2], s3 = csr[t + 3];
            float v0 = h1[s0 * 64 + lane];
            float v1 = h1[s1 * 64 + lane];
            float v2 = h1[s2 * 64 + lane];
            float v3 = h1[s3 * 64 + lane];
            acc += v0 + v1 + v2 + v3;
        }
        for (; t < re; ++t) acc += h1[csr[t] * 64 + lane];
        float inv = 1.0f / fmaxf((float)(re - rs), 1.0f);
        float hs = h1[node * 64 + lane];
        st[w][0][lane] = acc * inv;
        st[w][1][lane] = hs;
        float facc = bv;
        const float4* mp = (const float4*)st[w][0];
        const float4* hp = (const float4*)st[w][1];
#pragma unroll
        for (int k4 = 0; k4 < 16; k4++) {
            float4 m4 = mp[k4];
            float4 h4 = hp[k4];
            facc += m4.x * wl[k4 * 4 + 0] + m4.y * wl[k4 * 4 + 1] +
                    m4.z * wl[k4 * 4 + 2] + m4.w * wl[k4 * 4 + 3];
            facc += h4.x * wr[k4 * 4 + 0] + h4.y * wr[k4 * 4 + 1] +
                    h4.z * wr[k4 * 4 + 2] + h4.w * wr[k4 * 4 + 3];
        }
        pool += fmaxf(facc, 0.0f);
    }

    part[w][lane] = pool;
    __syncthreads();
    if (threadIdx.x < 64)
        atomicAdd(&gsum[threadIdx.x],
                  part[0][threadIdx.x] + part[1][threadIdx.x] +
                  part[2][threadIdx.x] + part[3][threadIdx.x]);
}

// ---------------------------------------------------------------------------
// Head: g = gsum/N; relu(g@fc1+b); @fc2+b; softmax
// ---------------------------------------------------------------------------
__global__ void head(const float* __restrict__ gsum,
                     const float* __restrict__ fc1W, const float* __restrict__ fc1b,
                     const float* __restrict__ fc2W, const float* __restrict__ fc2b,
                     float* __restrict__ out) {
    __shared__ float g[64];
    __shared__ float a1[64];
    __shared__ float a2[10];
    int j = threadIdx.x;
    g[j] = gsum[j] * (1.0f / (float)N_NODES);
    __syncthreads();
    float acc = fc1b[j];
    for (int k = 0; k < 64; k++) acc += g[k] * fc1W[k * 64 + j];
    a1[j] = fmaxf(acc, 0.0f);
    __syncthreads();
    if (j < 10) {
        float acc2 = fc2b[j];
        for (int k = 0; k < 64; k++) acc2 += a1[k] * fc2W[k * 10 + j];
        a2[j] = acc2;
    }
    __syncthreads();
    if (j == 0) {
        float mx = -1e30f;
        for (int i = 0; i < 10; i++) mx = fmaxf(mx, a2[i]);
        float s = 0.0f;
        float e[10];
        for (int i = 0; i < 10; i++) {
            e[i] = expf(a2[i] - mx);
            s += e[i];
        }
        float invs = 1.0f / s;
        for (int i = 0; i < 10; i++) out[i] = e[i] * invs;
    }
}

extern "C" void kernel_launch(void* const* d_in, const int* in_sizes, int n_in,
                              void* d_out, int out_size, void* d_ws, size_t ws_size,
                              hipStream_t stream) {
    const float* x    = (const float*)d_in[0];
    const int*   ei   = (const int*)d_in[1];
    const float* W1l  = (const float*)d_in[2];
    const float* b1   = (const float*)d_in[3];
    const float* W1r  = (const float*)d_in[4];
    const float* W2l  = (const float*)d_in[5];
    const float* b2   = (const float*)d_in[6];
    const float* W2r  = (const float*)d_in[7];
    const float* fc1W = (const float*)d_in[8];
    const float* fc1b = (const float*)d_in[9];
    const float* fc2W = (const float*)d_in[10];
    const float* fc2b = (const float*)d_in[11];
    float* out = (float*)d_out;

    const int* src = ei;             // edge_index[0]
    const int* dst = ei + N_EDGES;   // edge_index[1]

    // workspace layout: deg | cursor | gsum | row_start | bsum | boff | csr | h1
    int* deg       = (int*)d_ws;
    int* cursor    = deg + N_NODES;
    float* gsum    = (float*)(cursor + N_NODES);
    int* row_start = (int*)(gsum + 64);
    int* bsum      = row_start + N_NODES + 1;
    int* boff      = bsum + 512;
    int* csr       = boff + 512;
    float* h1      = (float*)(csr + N_EDGES);

    // zero deg + cursor + gsum (contiguous at front) each call
    hipMemsetAsync(d_ws, 0, (size_t)(2 * N_NODES + 64) * sizeof(float), stream);

    hist_kernel<<<2048, 256, 0, stream>>>(dst, deg);
    scanA<<<NBLK_SCAN, 256, 0, stream>>>(deg, bsum);
    scanB<<<1, 512, 0, stream>>>(bsum, boff);
    scanC<<<NBLK_SCAN, 256, 0, stream>>>(deg, boff, row_start);
    fill_kernel<<<2048, 256, 0, stream>>>(src, dst, row_start, cursor, csr);
    layer1<<<512, 256, 0, stream>>>(x, row_start, csr, W1l, b1, W1r, h1);
    layer2<<<1024, 256, 0, stream>>>(h1, row_start, csr, W2l, b2, W2r, gsum);
    head<<<1, 64, 0, stream>>>(gsum, fc1W, fc1b, fc2W, fc2b, out);
}

// Round 3
// 347.425 us; speedup vs baseline: 1.8110x; 1.3810x over previous
//
#include <hip/hip_runtime.h>
#include <hip/hip_bf16.h>
#include <hip/hip_fp16.h>

#define N_NODES 100000
#define N_EDGES 1600000
#define NBLK_SCAN ((N_NODES + 255) / 256)   // 391

__device__ inline float2 h2_to_f2(unsigned int u) {
    __half2 h = *reinterpret_cast<__half2*>(&u);
    return __half22float2(h);
}

// ---------------------------------------------------------------------------
// CSR build
// ---------------------------------------------------------------------------
__global__ void hist_kernel(const int* __restrict__ dst, int* __restrict__ deg) {
    int stride = gridDim.x * blockDim.x;
    for (int e = blockIdx.x * blockDim.x + threadIdx.x; e < N_EDGES; e += stride)
        atomicAdd(&deg[dst[e]], 1);
}

__global__ void scanA(const int* __restrict__ deg, int* __restrict__ bsum) {
    __shared__ int s[256];
    int gid = blockIdx.x * 256 + threadIdx.x;
    s[threadIdx.x] = (gid < N_NODES) ? deg[gid] : 0;
    __syncthreads();
    for (int d = 128; d > 0; d >>= 1) {
        if (threadIdx.x < d) s[threadIdx.x] += s[threadIdx.x + d];
        __syncthreads();
    }
    if (threadIdx.x == 0) bsum[blockIdx.x] = s[0];
}

__global__ void scanB(const int* __restrict__ bsum, int* __restrict__ boff) {
    __shared__ int s[512];
    int i = threadIdx.x;
    int v = (i < NBLK_SCAN) ? bsum[i] : 0;
    s[i] = v;
    __syncthreads();
    for (int d = 1; d < 512; d <<= 1) {
        int t = (i >= d) ? s[i - d] : 0;
        __syncthreads();
        s[i] += t;
        __syncthreads();
    }
    if (i < NBLK_SCAN) boff[i] = s[i] - v;
}

__global__ void scanC(const int* __restrict__ deg, const int* __restrict__ boff,
                      int* __restrict__ row_start) {
    __shared__ int s[256];
    int gid = blockIdx.x * 256 + threadIdx.x;
    int v = (gid < N_NODES) ? deg[gid] : 0;
    s[threadIdx.x] = v;
    __syncthreads();
    for (int d = 1; d < 256; d <<= 1) {
        int t = (threadIdx.x >= d) ? s[threadIdx.x - d] : 0;
        __syncthreads();
        s[threadIdx.x] += t;
        __syncthreads();
    }
    if (gid < N_NODES) row_start[gid] = boff[blockIdx.x] + s[threadIdx.x] - v;
    if (gid == 0) row_start[N_NODES] = N_EDGES;
}

__global__ void fill_kernel(const int* __restrict__ src, const int* __restrict__ dst,
                            const int* __restrict__ row_start, int* __restrict__ cursor,
                            int* __restrict__ csr) {
    int stride = gridDim.x * blockDim.x;
    for (int e = blockIdx.x * blockDim.x + threadIdx.x; e < N_EDGES; e += stride) {
        int d = dst[e];
        int pos = atomicAdd(&cursor[d], 1);
        csr[row_start[d] + pos] = src[e];
    }
}

// ---------------------------------------------------------------------------
// Layer 1 fused: one wave per node. Gather 8 neighbors per load instruction
// (8 lanes x 4B per x-row), shfl-reduce, 8->64 MLP with weights in regs,
// write h1 as fp16.
// ---------------------------------------------------------------------------
__global__ __launch_bounds__(256) void layer1(
    const float* __restrict__ x, const int* __restrict__ row_start,
    const int* __restrict__ csr, const float* __restrict__ W1l,
    const float* __restrict__ b1, const float* __restrict__ W1r,
    __half* __restrict__ h1h) {
    const int lane = threadIdx.x & 63;
    const int g = lane >> 3;       // neighbor slot 0..7
    const int sub = lane & 7;      // feature 0..7

    // weight column for output j=lane (8+8 regs)
    float wl1[8], wr1[8];
#pragma unroll
    for (int k = 0; k < 8; k++) {
        wl1[k] = W1l[k * 64 + lane];
        wr1[k] = W1r[k * 64 + lane];
    }
    float bv = b1[lane];
    asm volatile("" ::: "memory");  // pin weights in registers

    const int gwid = (blockIdx.x * blockDim.x + threadIdx.x) >> 6;
    const int nwaves = (gridDim.x * blockDim.x) >> 6;

    for (int node = gwid; node < N_NODES; node += nwaves) {
        int rs = row_start[node];
        int re = row_start[node + 1];
        float acc = 0.0f;
        int t = rs;
        for (; t + 16 <= re; t += 16) {
            int i0 = csr[t + g];
            int i1 = csr[t + 8 + g];
            float v0 = x[i0 * 8 + sub];
            float v1 = x[i1 * 8 + sub];
            acc += v0 + v1;
        }
        for (; t + 8 <= re; t += 8) {
            int i0 = csr[t + g];
            acc += x[i0 * 8 + sub];
        }
        int r = re - t;
        if (r > 0) {
            int ii = csr[(t + g < re) ? (t + g) : (re - 1)];
            float v = x[ii * 8 + sub];
            if (g < r) acc += v;
        }
        // reduce over the 8 neighbor slots
        acc += __shfl_xor(acc, 8);
        acc += __shfl_xor(acc, 16);
        acc += __shfl_xor(acc, 32);
        float inv = 1.0f / fmaxf((float)(re - rs), 1.0f);
        float mean = acc * inv;              // valid for feature `sub` on all lanes
        float xself = x[node * 8 + sub];
        // broadcast 8 features from lanes 0..7
        float m[8], xk[8];
#pragma unroll
        for (int k = 0; k < 8; k++) {
            m[k]  = __shfl(mean, k);
            xk[k] = __shfl(xself, k);
        }
        float a = bv;
#pragma unroll
        for (int k = 0; k < 8; k++)
            a += m[k] * wl1[k] + xk[k] * wr1[k];
        h1h[node * 64 + lane] = __float2half(fmaxf(a, 0.0f));
    }
}

// ---------------------------------------------------------------------------
// Layer 2 aggregation: one wave per node, fp16 rows, 4 neighbors per load
// instruction (16 lanes x 8B), 2x unrolled -> 8 rows in flight. Lean VGPRs.
// ---------------------------------------------------------------------------
__global__ __launch_bounds__(256) void agg2(
    const __half* __restrict__ h1h, const int* __restrict__ row_start,
    const int* __restrict__ csr, float* __restrict__ mean2) {
    const int lane = threadIdx.x & 63;
    const int g = lane >> 4;       // neighbor slot 0..3
    const int sub = lane & 15;     // feature group: feats 4*sub..4*sub+3

    const int gwid = (blockIdx.x * blockDim.x + threadIdx.x) >> 6;
    const int nwaves = (gridDim.x * blockDim.x) >> 6;

    for (int node = gwid; node < N_NODES; node += nwaves) {
        int rs = row_start[node];
        int re = row_start[node + 1];
        float4 acc = {0.f, 0.f, 0.f, 0.f};
        int t = rs;
        for (; t + 8 <= re; t += 8) {
            int i0 = csr[t + g];
            int i1 = csr[t + 4 + g];
            uint2 a = *(const uint2*)(h1h + i0 * 64 + sub * 4);
            uint2 b = *(const uint2*)(h1h + i1 * 64 + sub * 4);
            float2 a0 = h2_to_f2(a.x), a1 = h2_to_f2(a.y);
            float2 b0 = h2_to_f2(b.x), b1 = h2_to_f2(b.y);
            acc.x += a0.x + b0.x; acc.y += a0.y + b0.y;
            acc.z += a1.x + b1.x; acc.w += a1.y + b1.y;
        }
        for (; t + 4 <= re; t += 4) {
            int i0 = csr[t + g];
            uint2 a = *(const uint2*)(h1h + i0 * 64 + sub * 4);
            float2 a0 = h2_to_f2(a.x), a1 = h2_to_f2(a.y);
            acc.x += a0.x; acc.y += a0.y; acc.z += a1.x; acc.w += a1.y;
        }
        int r = re - t;
        if (r > 0) {
            int ii = csr[(t + g < re) ? (t + g) : (re - 1)];
            uint2 a = *(const uint2*)(h1h + ii * 64 + sub * 4);
            if (g < r) {
                float2 a0 = h2_to_f2(a.x), a1 = h2_to_f2(a.y);
                acc.x += a0.x; acc.y += a0.y; acc.z += a1.x; acc.w += a1.y;
            }
        }
        // reduce across the 4 neighbor slots
#pragma unroll
        for (int m = 16; m <= 32; m <<= 1) {
            acc.x += __shfl_xor(acc.x, m);
            acc.y += __shfl_xor(acc.y, m);
            acc.z += __shfl_xor(acc.z, m);
            acc.w += __shfl_xor(acc.w, m);
        }
        float inv = 1.0f / fmaxf((float)(re - rs), 1.0f);
        if (lane < 16) {
            float4 o = {acc.x * inv, acc.y * inv, acc.z * inv, acc.w * inv};
            *(float4*)(mean2 + node * 64 + sub * 4) = o;
        }
    }
}

// ---------------------------------------------------------------------------
// Layer 2 MLP + fused global mean pool. One wave per node; weight columns in
// registers (pinned by memory clobber); input rows broadcast via LDS float4.
// ---------------------------------------------------------------------------
__global__ __launch_bounds__(256, 2) void mlp2(
    const float* __restrict__ mean2, const __half* __restrict__ h1h,
    const int* __restrict__ row_start,  // unused, kept for symmetry
    const float* __restrict__ W2l, const float* __restrict__ b2,
    const float* __restrict__ W2r, float* __restrict__ gsum) {
    __shared__ float st[4][2][64];
    __shared__ float part[4][64];
    const int lane = threadIdx.x & 63;
    const int w = threadIdx.x >> 6;

    float wl[64], wr[64];
#pragma unroll
    for (int k = 0; k < 64; k++) {
        wl[k] = W2l[k * 64 + lane];
        wr[k] = W2r[k * 64 + lane];
    }
    float bv = b2[lane];
    asm volatile("" ::: "memory");  // forbid re-loading weights inside the loop

    const int gwid = (blockIdx.x * blockDim.x + threadIdx.x) >> 6;
    const int nwaves = (gridDim.x * blockDim.x) >> 6;
    float pool = 0.0f;

    for (int node = gwid; node < N_NODES; node += nwaves) {
        st[w][0][lane] = mean2[node * 64 + lane];
        st[w][1][lane] = __half2float(h1h[node * 64 + lane]);
        float facc = bv;
        const float4* mp = (const float4*)st[w][0];
        const float4* hp = (const float4*)st[w][1];
#pragma unroll
        for (int k4 = 0; k4 < 16; k4++) {
            float4 m4 = mp[k4];
            float4 h4 = hp[k4];
            facc += m4.x * wl[k4 * 4 + 0] + m4.y * wl[k4 * 4 + 1] +
                    m4.z * wl[k4 * 4 + 2] + m4.w * wl[k4 * 4 + 3];
            facc += h4.x * wr[k4 * 4 + 0] + h4.y * wr[k4 * 4 + 1] +
                    h4.z * wr[k4 * 4 + 2] + h4.w * wr[k4 * 4 + 3];
        }
        pool += fmaxf(facc, 0.0f);
    }

    part[w][lane] = pool;
    __syncthreads();
    if (threadIdx.x < 64)
        atomicAdd(&gsum[threadIdx.x],
                  part[0][threadIdx.x] + part[1][threadIdx.x] +
                  part[2][threadIdx.x] + part[3][threadIdx.x]);
}

// ---------------------------------------------------------------------------
// Head
// ---------------------------------------------------------------------------
__global__ void head(const float* __restrict__ gsum,
                     const float* __restrict__ fc1W, const float* __restrict__ fc1b,
                     const float* __restrict__ fc2W, const float* __restrict__ fc2b,
                     float* __restrict__ out) {
    __shared__ float g[64];
    __shared__ float a1[64];
    __shared__ float a2[10];
    int j = threadIdx.x;
    g[j] = gsum[j] * (1.0f / (float)N_NODES);
    __syncthreads();
    float acc = fc1b[j];
    for (int k = 0; k < 64; k++) acc += g[k] * fc1W[k * 64 + j];
    a1[j] = fmaxf(acc, 0.0f);
    __syncthreads();
    if (j < 10) {
        float acc2 = fc2b[j];
        for (int k = 0; k < 64; k++) acc2 += a1[k] * fc2W[k * 10 + j];
        a2[j] = acc2;
    }
    __syncthreads();
    if (j == 0) {
        float mx = -1e30f;
        for (int i = 0; i < 10; i++) mx = fmaxf(mx, a2[i]);
        float s = 0.0f;
        float e[10];
        for (int i = 0; i < 10; i++) {
            e[i] = expf(a2[i] - mx);
            s += e[i];
        }
        float invs = 1.0f / s;
        for (int i = 0; i < 10; i++) out[i] = e[i] * invs;
    }
}

extern "C" void kernel_launch(void* const* d_in, const int* in_sizes, int n_in,
                              void* d_out, int out_size, void* d_ws, size_t ws_size,
                              hipStream_t stream) {
    const float* x    = (const float*)d_in[0];
    const int*   ei   = (const int*)d_in[1];
    const float* W1l  = (const float*)d_in[2];
    const float* b1   = (const float*)d_in[3];
    const float* W1r  = (const float*)d_in[4];
    const float* W2l  = (const float*)d_in[5];
    const float* b2   = (const float*)d_in[6];
    const float* W2r  = (const float*)d_in[7];
    const float* fc1W = (const float*)d_in[8];
    const float* fc1b = (const float*)d_in[9];
    const float* fc2W = (const float*)d_in[10];
    const float* fc2b = (const float*)d_in[11];
    float* out = (float*)d_out;

    const int* src = ei;
    const int* dst = ei + N_EDGES;

    // workspace layout: deg | cursor | gsum | row_start | bsum | boff | csr | h1h | mean2
    int* deg       = (int*)d_ws;
    int* cursor    = deg + N_NODES;
    float* gsum    = (float*)(cursor + N_NODES);
    int* row_start = (int*)(gsum + 64);
    int* bsum      = row_start + N_NODES + 1;
    int* boff      = bsum + 512;
    int* csr       = boff + 512;
    __half* h1h    = (__half*)(csr + N_EDGES);                       // N*64 fp16 = 12.8 MB
    float* mean2   = (float*)(h1h + (size_t)N_NODES * 64);           // N*64 fp32 = 25.6 MB

    hipMemsetAsync(d_ws, 0, (size_t)(2 * N_NODES + 64) * sizeof(float), stream);

    hist_kernel<<<2048, 256, 0, stream>>>(dst, deg);
    scanA<<<NBLK_SCAN, 256, 0, stream>>>(deg, bsum);
    scanB<<<1, 512, 0, stream>>>(bsum, boff);
    scanC<<<NBLK_SCAN, 256, 0, stream>>>(deg, boff, row_start);
    fill_kernel<<<2048, 256, 0, stream>>>(src, dst, row_start, cursor, csr);
    layer1<<<2048, 256, 0, stream>>>(x, row_start, csr, W1l, b1, W1r, h1h);
    agg2<<<2048, 256, 0, stream>>>(h1h, row_start, csr, mean2);
    mlp2<<<1024, 256, 0, stream>>>(mean2, h1h, row_start, W2l, b2, W2r, gsum);
    head<<<1, 64, 0, stream>>>(gsum, fc1W, fc1b, fc2W, fc2b, out);
}

// Round 4
// 224.388 us; speedup vs baseline: 2.8040x; 1.5483x over previous
//
#include <hip/hip_runtime.h>
#include <hip/hip_bf16.h>
#include <hip/hip_fp16.h>

#define N_NODES 100000
#define N_EDGES 1600000
#define NBUCK ((N_NODES + 255) >> 8)   // 391 buckets of 256 nodes
#define CAP 8192                        // LDS staging capacity per bucket (avg cnt ~4092)

__device__ inline float2 h2_to_f2(unsigned int u) {
    __half2 h = *reinterpret_cast<__half2*>(&u);
    return __half22float2(h);
}

// ---------------------------------------------------------------------------
// CSR build, pass 1: per-bucket edge counts (LDS-privatized)
// ---------------------------------------------------------------------------
__global__ __launch_bounds__(256) void k_bhist(const int* __restrict__ dst,
                                               int* __restrict__ bcnt) {
    __shared__ int h[NBUCK];
    for (int i = threadIdx.x; i < NBUCK; i += 256) h[i] = 0;
    __syncthreads();
    int stride = gridDim.x * blockDim.x;
    for (int e = blockIdx.x * blockDim.x + threadIdx.x; e < N_EDGES; e += stride)
        atomicAdd(&h[dst[e] >> 8], 1);
    __syncthreads();
    for (int i = threadIdx.x; i < NBUCK; i += 256)
        if (h[i]) atomicAdd(&bcnt[i], h[i]);
}

// ---------------------------------------------------------------------------
// CSR build, pass 2: exclusive scan of bucket counts -> bstart, init cursors
// ---------------------------------------------------------------------------
__global__ void k_bscan(const int* __restrict__ bcnt, int* __restrict__ bstart,
                        int* __restrict__ bcursor) {
    __shared__ int s[512];
    int i = threadIdx.x;
    int v = (i < NBUCK) ? bcnt[i] : 0;
    s[i] = v;
    __syncthreads();
    for (int d = 1; d < 512; d <<= 1) {
        int t = (i >= d) ? s[i - d] : 0;
        __syncthreads();
        s[i] += t;
        __syncthreads();
    }
    if (i < NBUCK) {
        int ex = s[i] - v;
        bstart[i] = ex;
        bcursor[i] = ex;
    }
    if (i == 0) bstart[NBUCK] = N_EDGES;
}

// ---------------------------------------------------------------------------
// CSR build, pass 3: stage edges into bucket-major order. Per-block LDS
// histogram -> one global reservation atomic per (block,bucket) -> contiguous
// packed writes (local_node<<17 | src).
// ---------------------------------------------------------------------------
__global__ __launch_bounds__(256) void k_stage(const int* __restrict__ src,
                                               const int* __restrict__ dst,
                                               int* __restrict__ bcursor,
                                               unsigned int* __restrict__ stage) {
    __shared__ int h[NBUCK];
    __shared__ int base[NBUCK];
    __shared__ int cur[NBUCK];
    const int epb = (N_EDGES + gridDim.x - 1) / gridDim.x;
    const int c0 = blockIdx.x * epb;
    const int c1 = (c0 + epb < N_EDGES) ? (c0 + epb) : N_EDGES;

    for (int i = threadIdx.x; i < NBUCK; i += 256) { h[i] = 0; cur[i] = 0; }
    __syncthreads();
    for (int e = c0 + threadIdx.x; e < c1; e += 256)
        atomicAdd(&h[dst[e] >> 8], 1);
    __syncthreads();
    for (int i = threadIdx.x; i < NBUCK; i += 256)
        base[i] = h[i] ? atomicAdd(&bcursor[i], h[i]) : 0;
    __syncthreads();
    for (int e = c0 + threadIdx.x; e < c1; e += 256) {
        int d = dst[e];
        int b = d >> 8;
        int pos = atomicAdd(&cur[b], 1);
        stage[base[b] + pos] = ((unsigned int)(d & 255) << 17) | (unsigned int)src[e];
    }
}

// ---------------------------------------------------------------------------
// CSR build, pass 4: one block per bucket. LDS histogram over 256 nodes,
// LDS scan, permute into LDS, dump CSR segment coalesced. Emits row_start.
// ---------------------------------------------------------------------------
__global__ __launch_bounds__(256) void k_bsort(const unsigned int* __restrict__ stage,
                                               const int* __restrict__ bstart,
                                               int* __restrict__ csr,
                                               int* __restrict__ row_start) {
    __shared__ int off[256];
    __shared__ int cur[256];
    __shared__ unsigned int out[CAP];
    const int b = blockIdx.x;
    const int s = bstart[b];
    const int e = bstart[b + 1];
    const int cnt = e - s;
    const int tid = threadIdx.x;

    cur[tid] = 0;
    __syncthreads();
    for (int i = s + tid; i < e; i += 256)
        atomicAdd(&cur[stage[i] >> 17], 1);
    __syncthreads();
    int v = cur[tid];
    off[tid] = v;
    __syncthreads();
    for (int d = 1; d < 256; d <<= 1) {
        int t = (tid >= d) ? off[tid - d] : 0;
        __syncthreads();
        off[tid] += t;
        __syncthreads();
    }
    int ex = off[tid] - v;     // exclusive offset for node tid within bucket
    off[tid] = ex;
    cur[tid] = 0;
    int node = b * 256 + tid;
    if (node < N_NODES) row_start[node] = s + ex;
    if (b == 0 && tid == 0) row_start[N_NODES] = N_EDGES;
    __syncthreads();

    if (cnt <= CAP) {
        for (int i = s + tid; i < e; i += 256) {
            unsigned int p = stage[i];
            int l = p >> 17;
            int pos = off[l] + atomicAdd(&cur[l], 1);
            out[pos] = p & 0x1FFFFu;
        }
        __syncthreads();
        for (int i = tid; i < cnt; i += 256)
            csr[s + i] = (int)out[i];
    } else {  // overflow fallback (never taken for random graphs)
        for (int i = s + tid; i < e; i += 256) {
            unsigned int p = stage[i];
            int l = p >> 17;
            int pos = off[l] + atomicAdd(&cur[l], 1);
            csr[s + pos] = (int)(p & 0x1FFFFu);
        }
    }
}

// ---------------------------------------------------------------------------
// Layer 1 fused: one wave per node, 8 neighbors per load, shfl-reduce,
// 8->64 MLP with weights in regs, write h1 as fp16.
// ---------------------------------------------------------------------------
__global__ __launch_bounds__(256) void layer1(
    const float* __restrict__ x, const int* __restrict__ row_start,
    const int* __restrict__ csr, const float* __restrict__ W1l,
    const float* __restrict__ b1, const float* __restrict__ W1r,
    __half* __restrict__ h1h) {
    const int lane = threadIdx.x & 63;
    const int g = lane >> 3;
    const int sub = lane & 7;

    float wl1[8], wr1[8];
#pragma unroll
    for (int k = 0; k < 8; k++) {
        wl1[k] = W1l[k * 64 + lane];
        wr1[k] = W1r[k * 64 + lane];
    }
    float bv = b1[lane];
    asm volatile("" ::: "memory");

    const int gwid = (blockIdx.x * blockDim.x + threadIdx.x) >> 6;
    const int nwaves = (gridDim.x * blockDim.x) >> 6;

    for (int node = gwid; node < N_NODES; node += nwaves) {
        int rs = row_start[node];
        int re = row_start[node + 1];
        float acc = 0.0f;
        int t = rs;
        for (; t + 16 <= re; t += 16) {
            int i0 = csr[t + g];
            int i1 = csr[t + 8 + g];
            acc += x[i0 * 8 + sub] + x[i1 * 8 + sub];
        }
        for (; t + 8 <= re; t += 8) {
            int i0 = csr[t + g];
            acc += x[i0 * 8 + sub];
        }
        int r = re - t;
        if (r > 0) {
            int ii = csr[(t + g < re) ? (t + g) : (re - 1)];
            float v = x[ii * 8 + sub];
            if (g < r) acc += v;
        }
        acc += __shfl_xor(acc, 8);
        acc += __shfl_xor(acc, 16);
        acc += __shfl_xor(acc, 32);
        float inv = 1.0f / fmaxf((float)(re - rs), 1.0f);
        float mean = acc * inv;
        float xself = x[node * 8 + sub];
        float m[8], xk[8];
#pragma unroll
        for (int k = 0; k < 8; k++) {
            m[k]  = __shfl(mean, k);
            xk[k] = __shfl(xself, k);
        }
        float a = bv;
#pragma unroll
        for (int k = 0; k < 8; k++)
            a += m[k] * wl1[k] + xk[k] * wr1[k];
        h1h[node * 64 + lane] = __float2half(fmaxf(a, 0.0f));
    }
}

// ---------------------------------------------------------------------------
// Layer 2 aggregation: one wave per node, fp16 rows, 4 neighbors per load,
// 2x unrolled.
// ---------------------------------------------------------------------------
__global__ __launch_bounds__(256) void agg2(
    const __half* __restrict__ h1h, const int* __restrict__ row_start,
    const int* __restrict__ csr, float* __restrict__ mean2) {
    const int lane = threadIdx.x & 63;
    const int g = lane >> 4;
    const int sub = lane & 15;

    const int gwid = (blockIdx.x * blockDim.x + threadIdx.x) >> 6;
    const int nwaves = (gridDim.x * blockDim.x) >> 6;

    for (int node = gwid; node < N_NODES; node += nwaves) {
        int rs = row_start[node];
        int re = row_start[node + 1];
        float4 acc = {0.f, 0.f, 0.f, 0.f};
        int t = rs;
        for (; t + 8 <= re; t += 8) {
            int i0 = csr[t + g];
            int i1 = csr[t + 4 + g];
            uint2 a = *(const uint2*)(h1h + i0 * 64 + sub * 4);
            uint2 b = *(const uint2*)(h1h + i1 * 64 + sub * 4);
            float2 a0 = h2_to_f2(a.x), a1 = h2_to_f2(a.y);
            float2 b0 = h2_to_f2(b.x), b1 = h2_to_f2(b.y);
            acc.x += a0.x + b0.x; acc.y += a0.y + b0.y;
            acc.z += a1.x + b1.x; acc.w += a1.y + b1.y;
        }
        for (; t + 4 <= re; t += 4) {
            int i0 = csr[t + g];
            uint2 a = *(const uint2*)(h1h + i0 * 64 + sub * 4);
            float2 a0 = h2_to_f2(a.x), a1 = h2_to_f2(a.y);
            acc.x += a0.x; acc.y += a0.y; acc.z += a1.x; acc.w += a1.y;
        }
        int r = re - t;
        if (r > 0) {
            int ii = csr[(t + g < re) ? (t + g) : (re - 1)];
            uint2 a = *(const uint2*)(h1h + ii * 64 + sub * 4);
            if (g < r) {
                float2 a0 = h2_to_f2(a.x), a1 = h2_to_f2(a.y);
                acc.x += a0.x; acc.y += a0.y; acc.z += a1.x; acc.w += a1.y;
            }
        }
#pragma unroll
        for (int m = 16; m <= 32; m <<= 1) {
            acc.x += __shfl_xor(acc.x, m);
            acc.y += __shfl_xor(acc.y, m);
            acc.z += __shfl_xor(acc.z, m);
            acc.w += __shfl_xor(acc.w, m);
        }
        float inv = 1.0f / fmaxf((float)(re - rs), 1.0f);
        if (lane < 16) {
            float4 o = {acc.x * inv, acc.y * inv, acc.z * inv, acc.w * inv};
            *(float4*)(mean2 + node * 64 + sub * 4) = o;
        }
    }
}

// ---------------------------------------------------------------------------
// Layer 2 MLP + fused global mean pool.
// ---------------------------------------------------------------------------
__global__ __launch_bounds__(256, 2) void mlp2(
    const float* __restrict__ mean2, const __half* __restrict__ h1h,
    const float* __restrict__ W2l, const float* __restrict__ b2,
    const float* __restrict__ W2r, float* __restrict__ gsum) {
    __shared__ float st[4][2][64];
    __shared__ float part[4][64];
    const int lane = threadIdx.x & 63;
    const int w = threadIdx.x >> 6;

    float wl[64], wr[64];
#pragma unroll
    for (int k = 0; k < 64; k++) {
        wl[k] = W2l[k * 64 + lane];
        wr[k] = W2r[k * 64 + lane];
    }
    float bv = b2[lane];
    asm volatile("" ::: "memory");

    const int gwid = (blockIdx.x * blockDim.x + threadIdx.x) >> 6;
    const int nwaves = (gridDim.x * blockDim.x) >> 6;
    float pool = 0.0f;

    for (int node = gwid; node < N_NODES; node += nwaves) {
        st[w][0][lane] = mean2[node * 64 + lane];
        st[w][1][lane] = __half2float(h1h[node * 64 + lane]);
        float facc = bv;
        const float4* mp = (const float4*)st[w][0];
        const float4* hp = (const float4*)st[w][1];
#pragma unroll
        for (int k4 = 0; k4 < 16; k4++) {
            float4 m4 = mp[k4];
            float4 h4 = hp[k4];
            facc += m4.x * wl[k4 * 4 + 0] + m4.y * wl[k4 * 4 + 1] +
                    m4.z * wl[k4 * 4 + 2] + m4.w * wl[k4 * 4 + 3];
            facc += h4.x * wr[k4 * 4 + 0] + h4.y * wr[k4 * 4 + 1] +
                    h4.z * wr[k4 * 4 + 2] + h4.w * wr[k4 * 4 + 3];
        }
        pool += fmaxf(facc, 0.0f);
    }

    part[w][lane] = pool;
    __syncthreads();
    if (threadIdx.x < 64)
        atomicAdd(&gsum[threadIdx.x],
                  part[0][threadIdx.x] + part[1][threadIdx.x] +
                  part[2][threadIdx.x] + part[3][threadIdx.x]);
}

// ---------------------------------------------------------------------------
// Head
// ---------------------------------------------------------------------------
__global__ void head(const float* __restrict__ gsum,
                     const float* __restrict__ fc1W, const float* __restrict__ fc1b,
                     const float* __restrict__ fc2W, const float* __restrict__ fc2b,
                     float* __restrict__ out) {
    __shared__ float g[64];
    __shared__ float a1[64];
    __shared__ float a2[10];
    int j = threadIdx.x;
    g[j] = gsum[j] * (1.0f / (float)N_NODES);
    __syncthreads();
    float acc = fc1b[j];
    for (int k = 0; k < 64; k++) acc += g[k] * fc1W[k * 64 + j];
    a1[j] = fmaxf(acc, 0.0f);
    __syncthreads();
    if (j < 10) {
        float acc2 = fc2b[j];
        for (int k = 0; k < 64; k++) acc2 += a1[k] * fc2W[k * 10 + j];
        a2[j] = acc2;
    }
    __syncthreads();
    if (j == 0) {
        float mx = -1e30f;
        for (int i = 0; i < 10; i++) mx = fmaxf(mx, a2[i]);
        float s = 0.0f;
        float e[10];
        for (int i = 0; i < 10; i++) {
            e[i] = expf(a2[i] - mx);
            s += e[i];
        }
        float invs = 1.0f / s;
        for (int i = 0; i < 10; i++) out[i] = e[i] * invs;
    }
}

extern "C" void kernel_launch(void* const* d_in, const int* in_sizes, int n_in,
                              void* d_out, int out_size, void* d_ws, size_t ws_size,
                              hipStream_t stream) {
    const float* x    = (const float*)d_in[0];
    const int*   ei   = (const int*)d_in[1];
    const float* W1l  = (const float*)d_in[2];
    const float* b1   = (const float*)d_in[3];
    const float* W1r  = (const float*)d_in[4];
    const float* W2l  = (const float*)d_in[5];
    const float* b2   = (const float*)d_in[6];
    const float* W2r  = (const float*)d_in[7];
    const float* fc1W = (const float*)d_in[8];
    const float* fc1b = (const float*)d_in[9];
    const float* fc2W = (const float*)d_in[10];
    const float* fc2b = (const float*)d_in[11];
    float* out = (float*)d_out;

    const int* src = ei;
    const int* dst = ei + N_EDGES;

    // workspace layout: gsum(64) | bcnt(NB) | row_start(N+1) | bstart(NB+1) |
    //                   bcursor(NB) | csr(E) | h1h(N*64 half) | mean2(N*64 f32)
    // stage aliases mean2 (disjoint lifetimes: stage dead after k_bsort,
    // mean2 written by agg2 afterwards).
    float* gsum    = (float*)d_ws;
    int* bcnt      = (int*)(gsum + 64);
    int* row_start = bcnt + NBUCK;
    int* bstart    = row_start + N_NODES + 1;
    int* bcursor   = bstart + NBUCK + 1;
    int* csr       = bcursor + NBUCK;
    __half* h1h    = (__half*)(csr + N_EDGES);
    float* mean2   = (float*)(h1h + (size_t)N_NODES * 64);
    unsigned int* stage = (unsigned int*)mean2;

    // zero gsum + bcnt (adjacent at the front)
    hipMemsetAsync(d_ws, 0, (size_t)(64 + NBUCK) * sizeof(int), stream);

    k_bhist<<<512, 256, 0, stream>>>(dst, bcnt);
    k_bscan<<<1, 512, 0, stream>>>(bcnt, bstart, bcursor);
    k_stage<<<256, 256, 0, stream>>>(src, dst, bcursor, stage);
    k_bsort<<<NBUCK, 256, 0, stream>>>(stage, bstart, csr, row_start);
    layer1<<<2048, 256, 0, stream>>>(x, row_start, csr, W1l, b1, W1r, h1h);
    agg2<<<2048, 256, 0, stream>>>(h1h, row_start, csr, mean2);
    mlp2<<<1024, 256, 0, stream>>>(mean2, h1h, W2l, b2, W2r, gsum);
    head<<<1, 64, 0, stream>>>(gsum, fc1W, fc1b, fc2W, fc2b, out);
}